// Round 1
// baseline (5003.767 us; speedup 1.0000x reference)
//
#include <hip/hip_runtime.h>
#include <hip/hip_bf16.h>
#include <cmath>

#define D_MODEL 1024
#define NHEADS  16
#define DK      64
#define BATCH   32
#define SEQ     512
#define M_TOTAL (BATCH * SEQ)   // 16384
#define LIN_EPS 1e-6f

// ---------------------------------------------------------------------------
// GEMM: C = A[M,K] @ W[K,N] + bias, optional phi epilogue + BHND permute.
// mode 0: plain row-major [M,N] out
// mode 1: phi(elu+1) epilogue, store to [B,H,N,DK]
// mode 2: plain epilogue, store to [B,H,N,DK]
// Tile 64x64, K-chunk 16, 16x16 threads, 4x4 accum per thread.
// ---------------------------------------------------------------------------
__global__ __launch_bounds__(256)
void gemm_tile(const float* __restrict__ A, const float* __restrict__ W,
               const float* __restrict__ bias, float* __restrict__ out,
               int M, int K, int N, int mode)
{
    __shared__ float As[64][20];   // pad 20 keeps float4-alignable, 2-way max conflict
    __shared__ float Bs[16][64];

    const int tx = threadIdx.x, ty = threadIdx.y;
    const int t  = ty * 16 + tx;
    const int rowBase = blockIdx.y * 64;
    const int colBase = blockIdx.x * 64;

    float4 acc[4];
    acc[0] = acc[1] = acc[2] = acc[3] = make_float4(0.f, 0.f, 0.f, 0.f);

    const int arow = t >> 2;          // 0..63
    const int acol = (t & 3) * 4;     // 0,4,8,12
    const int brow = t >> 4;          // 0..15
    const int bcol = (t & 15) * 4;    // 0..60

    for (int k0 = 0; k0 < K; k0 += 16) {
        float4 av = *(const float4*)&A[(size_t)(rowBase + arow) * K + k0 + acol];
        As[arow][acol + 0] = av.x;
        As[arow][acol + 1] = av.y;
        As[arow][acol + 2] = av.z;
        As[arow][acol + 3] = av.w;
        *(float4*)&Bs[brow][bcol] =
            *(const float4*)&W[(size_t)(k0 + brow) * N + colBase + bcol];
        __syncthreads();
        #pragma unroll
        for (int kk = 0; kk < 16; kk++) {
            float4 b4 = *(float4*)&Bs[kk][tx * 4];
            #pragma unroll
            for (int i = 0; i < 4; i++) {
                float a = As[ty * 4 + i][kk];
                acc[i].x += a * b4.x;
                acc[i].y += a * b4.y;
                acc[i].z += a * b4.z;
                acc[i].w += a * b4.w;
            }
        }
        __syncthreads();
    }

    float4 bv = *(const float4*)&bias[colBase + tx * 4];
    #pragma unroll
    for (int i = 0; i < 4; i++) {
        float4 c = acc[i];
        c.x += bv.x; c.y += bv.y; c.z += bv.z; c.w += bv.w;
        if (mode == 1) {  // phi = elu(x)+1 : x>0 ? x+1 : exp(x)
            c.x = (c.x > 0.f) ? c.x + 1.f : expf(c.x);
            c.y = (c.y > 0.f) ? c.y + 1.f : expf(c.y);
            c.z = (c.z > 0.f) ? c.z + 1.f : expf(c.z);
            c.w = (c.w > 0.f) ? c.w + 1.f : expf(c.w);
        }
        const int m = rowBase + ty * 4 + i;
        const int cfull = colBase + tx * 4;
        if (mode == 0) {
            *(float4*)&out[(size_t)m * N + cfull] = c;
        } else {
            const int b = m >> 9;         // SEQ = 512
            const int n = m & 511;
            const int h = cfull >> 6;     // DK = 64
            const int d = cfull & 63;
            *(float4*)&out[((size_t)((b * NHEADS + h) * SEQ + n)) * DK + d] = c;
        }
    }
}

// ---------------------------------------------------------------------------
// Linear attention per (b,h): kv[d][e] = sum_n kf[n,d]*v[n,e]; ksum[d];
// out[n,e] = (sum_d qf[n,d]*kv[d,e]) / (qf[n,:].ksum + eps)
// written to attn[B,N,H*DK] (back to [B,N,D_MODEL] layout).
// One block per (b,h), 256 threads.
// ---------------------------------------------------------------------------
__global__ __launch_bounds__(256)
void attn_kernel(const float* __restrict__ qf, const float* __restrict__ kf,
                 const float* __restrict__ v, float* __restrict__ attn)
{
    __shared__ float kfS[32][64];
    __shared__ float vS[32][64];
    __shared__ float kvS[64][68];   // pad 4 -> float4-aligned columns
    __shared__ float ksumS[64];

    const int bh = blockIdx.x;          // 0..511
    const int b  = bh >> 4;
    const int h  = bh & 15;
    const size_t base = (size_t)bh * SEQ * DK;
    const float* qfp = qf + base;
    const float* kfp = kf + base;
    const float* vp  = v  + base;

    const int t  = threadIdx.x;         // 0..255
    const int tr = t >> 4;              // 0..15 -> d-group
    const int tc = t & 15;              // 0..15 -> e-group

    float acc[4][4];
    #pragma unroll
    for (int i = 0; i < 4; i++)
        #pragma unroll
        for (int j = 0; j < 4; j++) acc[i][j] = 0.f;
    float ks[4] = {0.f, 0.f, 0.f, 0.f};

    const int lr = t >> 3;              // 0..31
    const int lc = (t & 7) * 8;         // 0..56

    for (int n0 = 0; n0 < SEQ; n0 += 32) {
        *(float4*)&kfS[lr][lc]     = *(const float4*)&kfp[(size_t)(n0 + lr) * DK + lc];
        *(float4*)&kfS[lr][lc + 4] = *(const float4*)&kfp[(size_t)(n0 + lr) * DK + lc + 4];
        *(float4*)&vS[lr][lc]      = *(const float4*)&vp[(size_t)(n0 + lr) * DK + lc];
        *(float4*)&vS[lr][lc + 4]  = *(const float4*)&vp[(size_t)(n0 + lr) * DK + lc + 4];
        __syncthreads();
        #pragma unroll 8
        for (int nn = 0; nn < 32; nn++) {
            float a0 = kfS[nn][tr * 4 + 0];
            float a1 = kfS[nn][tr * 4 + 1];
            float a2 = kfS[nn][tr * 4 + 2];
            float a3 = kfS[nn][tr * 4 + 3];
            float4 b4 = *(float4*)&vS[nn][tc * 4];
            acc[0][0] += a0 * b4.x; acc[0][1] += a0 * b4.y; acc[0][2] += a0 * b4.z; acc[0][3] += a0 * b4.w;
            acc[1][0] += a1 * b4.x; acc[1][1] += a1 * b4.y; acc[1][2] += a1 * b4.z; acc[1][3] += a1 * b4.w;
            acc[2][0] += a2 * b4.x; acc[2][1] += a2 * b4.y; acc[2][2] += a2 * b4.z; acc[2][3] += a2 * b4.w;
            acc[3][0] += a3 * b4.x; acc[3][1] += a3 * b4.y; acc[3][2] += a3 * b4.z; acc[3][3] += a3 * b4.w;
            if (tc == 0) { ks[0] += a0; ks[1] += a1; ks[2] += a2; ks[3] += a3; }
        }
        __syncthreads();
    }

    #pragma unroll
    for (int i = 0; i < 4; i++)
        #pragma unroll
        for (int j = 0; j < 4; j++)
            kvS[tr * 4 + i][tc * 4 + j] = acc[i][j];
    if (tc == 0) {
        #pragma unroll
        for (int i = 0; i < 4; i++) ksumS[tr * 4 + i] = ks[i];
    }
    __syncthreads();

    // phase 2: each thread handles rows n = t and t + 256
    #pragma unroll
    for (int rep = 0; rep < 2; rep++) {
        const int n = t + rep * 256;
        const float* qrow = qfp + (size_t)n * DK;
        float q[64];
        #pragma unroll
        for (int d4 = 0; d4 < 64; d4 += 4) {
            float4 qv = *(const float4*)&qrow[d4];
            q[d4] = qv.x; q[d4 + 1] = qv.y; q[d4 + 2] = qv.z; q[d4 + 3] = qv.w;
        }
        float denom = LIN_EPS;
        #pragma unroll
        for (int d = 0; d < 64; d++) denom += q[d] * ksumS[d];
        const float inv = 1.f / denom;

        float* dst = attn + ((size_t)(b * SEQ + n)) * D_MODEL + h * DK;
        #pragma unroll
        for (int e0 = 0; e0 < 64; e0 += 4) {
            float4 o = make_float4(0.f, 0.f, 0.f, 0.f);
            #pragma unroll
            for (int d = 0; d < 64; d++) {
                float qd = q[d];
                o.x += qd * kvS[d][e0 + 0];
                o.y += qd * kvS[d][e0 + 1];
                o.z += qd * kvS[d][e0 + 2];
                o.w += qd * kvS[d][e0 + 3];
            }
            o.x *= inv; o.y *= inv; o.z *= inv; o.w *= inv;
            *(float4*)&dst[e0] = o;
        }
    }
}

extern "C" void kernel_launch(void* const* d_in, const int* in_sizes, int n_in,
                              void* d_out, int out_size, void* d_ws, size_t ws_size,
                              hipStream_t stream)
{
    const float* x   = (const float*)d_in[0];
    const float* W_q = (const float*)d_in[1];
    const float* b_q = (const float*)d_in[2];
    const float* W_k = (const float*)d_in[3];
    const float* b_k = (const float*)d_in[4];
    const float* W_v = (const float*)d_in[5];
    const float* b_v = (const float*)d_in[6];
    const float* W_o = (const float*)d_in[7];
    const float* b_o = (const float*)d_in[8];
    float* out = (float*)d_out;

    const size_t MN = (size_t)M_TOTAL * D_MODEL;   // 16,777,216 floats
    float* qf   = (float*)d_ws;
    float* kf   = qf + MN;
    float* v    = kf + MN;
    float* attn = v + MN;

    dim3 blk(16, 16);
    dim3 grd(D_MODEL / 64, M_TOTAL / 64);   // (16, 256)

    gemm_tile<<<grd, blk, 0, stream>>>(x, W_q, b_q, qf, M_TOTAL, D_MODEL, D_MODEL, 1);
    gemm_tile<<<grd, blk, 0, stream>>>(x, W_k, b_k, kf, M_TOTAL, D_MODEL, D_MODEL, 1);
    gemm_tile<<<grd, blk, 0, stream>>>(x, W_v, b_v, v,  M_TOTAL, D_MODEL, D_MODEL, 2);

    attn_kernel<<<dim3(BATCH * NHEADS), dim3(256), 0, stream>>>(qf, kf, v, attn);

    gemm_tile<<<grd, blk, 0, stream>>>(attn, W_o, b_o, out, M_TOTAL, D_MODEL, D_MODEL, 0);
}

// Round 2
// 2158.279 us; speedup vs baseline: 2.3184x; 2.3184x over previous
//
#include <hip/hip_runtime.h>
#include <hip/hip_bf16.h>
#include <cmath>

#define D_MODEL 1024
#define NHEADS  16
#define DK      64
#define BATCH   32
#define SEQ     512
#define M_TOTAL (BATCH * SEQ)   // 16384
#define LIN_EPS 1e-6f

// ---------------------------------------------------------------------------
// GEMM: C = A[M,K] @ W[K,N] + bias, optional phi epilogue + BHND permute.
// mode 0: plain row-major [M,N] out
// mode 1: phi(elu+1) epilogue, store to [B,H,N,DK]
// mode 2: plain epilogue, store to [B,H,N,DK]
// Tile 64x64, K-chunk 16, 16x16 threads, 4x4 accum per thread.
// ---------------------------------------------------------------------------
__global__ __launch_bounds__(256)
void gemm_tile(const float* __restrict__ A, const float* __restrict__ W,
               const float* __restrict__ bias, float* __restrict__ out,
               int M, int K, int N, int mode)
{
    __shared__ float As[64][20];
    __shared__ float Bs[16][64];

    const int tx = threadIdx.x, ty = threadIdx.y;
    const int t  = ty * 16 + tx;
    const int rowBase = blockIdx.y * 64;
    const int colBase = blockIdx.x * 64;

    float4 acc[4];
    acc[0] = acc[1] = acc[2] = acc[3] = make_float4(0.f, 0.f, 0.f, 0.f);

    const int arow = t >> 2;          // 0..63
    const int acol = (t & 3) * 4;     // 0,4,8,12
    const int brow = t >> 4;          // 0..15
    const int bcol = (t & 15) * 4;    // 0..60

    for (int k0 = 0; k0 < K; k0 += 16) {
        float4 av = *(const float4*)&A[(size_t)(rowBase + arow) * K + k0 + acol];
        As[arow][acol + 0] = av.x;
        As[arow][acol + 1] = av.y;
        As[arow][acol + 2] = av.z;
        As[arow][acol + 3] = av.w;
        *(float4*)&Bs[brow][bcol] =
            *(const float4*)&W[(size_t)(k0 + brow) * N + colBase + bcol];
        __syncthreads();
        #pragma unroll
        for (int kk = 0; kk < 16; kk++) {
            float4 b4 = *(float4*)&Bs[kk][tx * 4];
            #pragma unroll
            for (int i = 0; i < 4; i++) {
                float a = As[ty * 4 + i][kk];
                acc[i].x += a * b4.x;
                acc[i].y += a * b4.y;
                acc[i].z += a * b4.z;
                acc[i].w += a * b4.w;
            }
        }
        __syncthreads();
    }

    float4 bv = *(const float4*)&bias[colBase + tx * 4];
    #pragma unroll
    for (int i = 0; i < 4; i++) {
        float4 c = acc[i];
        c.x += bv.x; c.y += bv.y; c.z += bv.z; c.w += bv.w;
        if (mode == 1) {  // phi = elu(x)+1 : x>0 ? x+1 : exp(x)
            c.x = (c.x > 0.f) ? c.x + 1.f : expf(c.x);
            c.y = (c.y > 0.f) ? c.y + 1.f : expf(c.y);
            c.z = (c.z > 0.f) ? c.z + 1.f : expf(c.z);
            c.w = (c.w > 0.f) ? c.w + 1.f : expf(c.w);
        }
        const int m = rowBase + ty * 4 + i;
        const int cfull = colBase + tx * 4;
        if (mode == 0) {
            *(float4*)&out[(size_t)m * N + cfull] = c;
        } else {
            const int b = m >> 9;         // SEQ = 512
            const int n = m & 511;
            const int h = cfull >> 6;     // DK = 64
            const int d = cfull & 63;
            *(float4*)&out[((size_t)((b * NHEADS + h) * SEQ + n)) * DK + d] = c;
        }
    }
}

// ---------------------------------------------------------------------------
// Linear attention per (b,h):
//   phase 1: kv[d][e] = sum_n kf[n,d]*v[n,e];  ksum[d] = sum_n kf[n,d]
//   phase 2: out[n,e] = (sum_d qf[n,d]*kv[d,e]) / (qf[n,:].ksum + eps)
// Phase 2 is LDS-tiled: 64-row q tiles staged in LDS, each thread owns a
// 4x4 output patch — no per-thread q[64] array (R0 spilled at VGPR=256,
// 6.1 GB scratch traffic, 2.76 ms).
// One block per (b,h), 256 threads.
// ---------------------------------------------------------------------------
__global__ __launch_bounds__(256)
void attn_kernel(const float* __restrict__ qf, const float* __restrict__ kf,
                 const float* __restrict__ v, float* __restrict__ attn)
{
    __shared__ float kfS[32][64];
    __shared__ float vS[32][64];
    __shared__ float kvS[64][68];
    __shared__ float ksumS[64];
    __shared__ float qS[64][68];

    const int bh = blockIdx.x;          // 0..511
    const int b  = bh >> 4;
    const int h  = bh & 15;
    const size_t base = (size_t)bh * SEQ * DK;
    const float* qfp = qf + base;
    const float* kfp = kf + base;
    const float* vp  = v  + base;

    const int t  = threadIdx.x;         // 0..255
    const int tr = t >> 4;              // 0..15
    const int tc = t & 15;              // 0..15

    // ---- phase 1: kv + ksum ----
    float acc[4][4];
    #pragma unroll
    for (int i = 0; i < 4; i++)
        #pragma unroll
        for (int j = 0; j < 4; j++) acc[i][j] = 0.f;
    float ks[4] = {0.f, 0.f, 0.f, 0.f};

    const int lr = t >> 3;              // 0..31
    const int lc = (t & 7) * 8;         // 0..56

    for (int n0 = 0; n0 < SEQ; n0 += 32) {
        *(float4*)&kfS[lr][lc]     = *(const float4*)&kfp[(size_t)(n0 + lr) * DK + lc];
        *(float4*)&kfS[lr][lc + 4] = *(const float4*)&kfp[(size_t)(n0 + lr) * DK + lc + 4];
        *(float4*)&vS[lr][lc]      = *(const float4*)&vp[(size_t)(n0 + lr) * DK + lc];
        *(float4*)&vS[lr][lc + 4]  = *(const float4*)&vp[(size_t)(n0 + lr) * DK + lc + 4];
        __syncthreads();
        #pragma unroll 8
        for (int nn = 0; nn < 32; nn++) {
            float a0 = kfS[nn][tr * 4 + 0];
            float a1 = kfS[nn][tr * 4 + 1];
            float a2 = kfS[nn][tr * 4 + 2];
            float a3 = kfS[nn][tr * 4 + 3];
            float4 b4 = *(float4*)&vS[nn][tc * 4];
            acc[0][0] += a0 * b4.x; acc[0][1] += a0 * b4.y; acc[0][2] += a0 * b4.z; acc[0][3] += a0 * b4.w;
            acc[1][0] += a1 * b4.x; acc[1][1] += a1 * b4.y; acc[1][2] += a1 * b4.z; acc[1][3] += a1 * b4.w;
            acc[2][0] += a2 * b4.x; acc[2][1] += a2 * b4.y; acc[2][2] += a2 * b4.z; acc[2][3] += a2 * b4.w;
            acc[3][0] += a3 * b4.x; acc[3][1] += a3 * b4.y; acc[3][2] += a3 * b4.z; acc[3][3] += a3 * b4.w;
            if (tc == 0) { ks[0] += a0; ks[1] += a1; ks[2] += a2; ks[3] += a3; }
        }
        __syncthreads();
    }

    #pragma unroll
    for (int i = 0; i < 4; i++)
        #pragma unroll
        for (int j = 0; j < 4; j++)
            kvS[tr * 4 + i][tc * 4 + j] = acc[i][j];
    if (tc == 0) {
        #pragma unroll
        for (int i = 0; i < 4; i++) ksumS[tr * 4 + i] = ks[i];
    }

    // ---- phase 2: out = qf @ kv / (qf . ksum + eps), LDS-tiled ----
    const int qlr = t >> 2;             // 0..63
    const int qlc = (t & 3) * 16;       // 0,16,32,48

    for (int n0 = 0; n0 < SEQ; n0 += 64) {
        __syncthreads();                 // kvS ready (first iter) / prev tile done
        #pragma unroll
        for (int j = 0; j < 16; j += 4)
            *(float4*)&qS[qlr][qlc + j] =
                *(const float4*)&qfp[(size_t)(n0 + qlr) * DK + qlc + j];
        __syncthreads();

        float4 o[4];
        float den[4];
        #pragma unroll
        for (int i = 0; i < 4; i++) {
            o[i] = make_float4(0.f, 0.f, 0.f, 0.f);
            den[i] = LIN_EPS;
        }
        #pragma unroll 4
        for (int d = 0; d < 64; d++) {
            float4 b4 = *(float4*)&kvS[d][tc * 4];
            float ksd = ksumS[d];
            #pragma unroll
            for (int i = 0; i < 4; i++) {
                float a = qS[tr * 4 + i][d];
                o[i].x += a * b4.x;
                o[i].y += a * b4.y;
                o[i].z += a * b4.z;
                o[i].w += a * b4.w;
                den[i] += a * ksd;
            }
        }
        #pragma unroll
        for (int i = 0; i < 4; i++) {
            const float inv = 1.f / den[i];
            float4 oo = o[i];
            oo.x *= inv; oo.y *= inv; oo.z *= inv; oo.w *= inv;
            const int n = n0 + tr * 4 + i;
            float* dst = attn + ((size_t)(b * SEQ + n)) * D_MODEL + h * DK;
            *(float4*)&dst[tc * 4] = oo;
        }
    }
}

extern "C" void kernel_launch(void* const* d_in, const int* in_sizes, int n_in,
                              void* d_out, int out_size, void* d_ws, size_t ws_size,
                              hipStream_t stream)
{
    const float* x   = (const float*)d_in[0];
    const float* W_q = (const float*)d_in[1];
    const float* b_q = (const float*)d_in[2];
    const float* W_k = (const float*)d_in[3];
    const float* b_k = (const float*)d_in[4];
    const float* W_v = (const float*)d_in[5];
    const float* b_v = (const float*)d_in[6];
    const float* W_o = (const float*)d_in[7];
    const float* b_o = (const float*)d_in[8];
    float* out = (float*)d_out;

    const size_t MN = (size_t)M_TOTAL * D_MODEL;   // 16,777,216 floats
    float* qf   = (float*)d_ws;
    float* kf   = qf + MN;
    float* v    = kf + MN;
    float* attn = v + MN;

    dim3 blk(16, 16);
    dim3 grd(D_MODEL / 64, M_TOTAL / 64);   // (16, 256)

    gemm_tile<<<grd, blk, 0, stream>>>(x, W_q, b_q, qf, M_TOTAL, D_MODEL, D_MODEL, 1);
    gemm_tile<<<grd, blk, 0, stream>>>(x, W_k, b_k, kf, M_TOTAL, D_MODEL, D_MODEL, 1);
    gemm_tile<<<grd, blk, 0, stream>>>(x, W_v, b_v, v,  M_TOTAL, D_MODEL, D_MODEL, 2);

    attn_kernel<<<dim3(BATCH * NHEADS), dim3(256), 0, stream>>>(qf, kf, v, attn);

    gemm_tile<<<grd, blk, 0, stream>>>(attn, W_o, b_o, out, M_TOTAL, D_MODEL, D_MODEL, 0);
}

// Round 5
// 503.481 us; speedup vs baseline: 9.9383x; 4.2867x over previous
//
#include <hip/hip_runtime.h>
#include <hip/hip_bf16.h>
#include <cmath>

#define D_MODEL 1024
#define NHEADS  16
#define DK      64
#define BATCH   32
#define SEQ     512
#define M_TOTAL (BATCH * SEQ)   // 16384
#define LIN_EPS 1e-6f

typedef __attribute__((ext_vector_type(8))) short short8;
typedef __attribute__((ext_vector_type(4))) short short4v;
typedef __attribute__((ext_vector_type(4))) float floatx4;

__device__ inline short f2bf(float f) {
    __hip_bfloat16 h = __float2bfloat16(f);
    return *reinterpret_cast<short*>(&h);
}
__device__ inline float bf2f(short s) {
    unsigned int u = ((unsigned int)(unsigned short)s) << 16;
    union { unsigned int u; float f; } c; c.u = u;
    return c.f;
}

// ---------------------------------------------------------------------------
// fp32 -> bf16 cast, vectorized
// ---------------------------------------------------------------------------
__global__ __launch_bounds__(256)
void cast_bf16(const float* __restrict__ in, short* __restrict__ out, int n4)
{
    int i = blockIdx.x * 256 + threadIdx.x;
    if (i >= n4) return;
    float4 f = *(const float4*)&in[(size_t)i * 4];
    short4v s;
    s.x = f2bf(f.x); s.y = f2bf(f.y); s.z = f2bf(f.z); s.w = f2bf(f.w);
    *(short4v*)&out[(size_t)i * 4] = s;
}

// ---------------------------------------------------------------------------
// W[K][N] fp32 -> Wt[N][K] bf16 (1024x1024)
// ---------------------------------------------------------------------------
__global__ __launch_bounds__(256)
void transpose_w(const float* __restrict__ W, short* __restrict__ Wt)
{
    __shared__ float tile[32][33];
    const int tx = threadIdx.x, ty = threadIdx.y;   // 32 x 8
    const int nb = blockIdx.x * 32, kb = blockIdx.y * 32;
    #pragma unroll
    for (int r = 0; r < 32; r += 8)
        tile[ty + r][tx] = W[(size_t)(kb + ty + r) * D_MODEL + nb + tx];
    __syncthreads();
    #pragma unroll
    for (int r = 0; r < 32; r += 8)
        Wt[(size_t)(nb + ty + r) * D_MODEL + kb + tx] = f2bf(tile[tx][ty + r]);
}

// ---------------------------------------------------------------------------
// NT bf16 MFMA GEMM: C[M,1024] = A[M,1024] @ Bt[1024,1024]^T  (+bias)
// 128x128 tile, BK=32, 256 thr (4 waves), wave = 64x64 quadrant =
// 4x4 mfma_f32_16x16x32_bf16. Register-path LDS staging.
// mode 0: fp32 out [M][1024]
// mode 1: phi(elu+1), bf16 out permuted [B,H,N,DK]
// mode 2: bf16 out permuted [B,H,N,DK]
// ---------------------------------------------------------------------------
__global__ __launch_bounds__(256)
void gemm_nt_bf16(const short* __restrict__ A, const short* __restrict__ Bt,
                  const float* __restrict__ bias, float* __restrict__ outF,
                  short* __restrict__ outB, int mode)
{
    constexpr int K = 1024;
    constexpr int N = 1024;
    __shared__ short As[128 * 32];
    __shared__ short Bs[128 * 32];

    const int t    = threadIdx.x;
    const int wave = t >> 6;
    const int lane = t & 63;
    const int rowBase = blockIdx.y * 128;
    const int colBase = blockIdx.x * 128;
    const int wm = (wave >> 1) * 64;
    const int wn = (wave & 1) * 64;

    floatx4 acc[4][4];
    #pragma unroll
    for (int i = 0; i < 4; i++)
        #pragma unroll
        for (int j = 0; j < 4; j++) acc[i][j] = (floatx4){0.f, 0.f, 0.f, 0.f};

    const int srow = t >> 2;          // 0..63
    const int skq  = (t & 3) * 8;     // 0,8,16,24
    const int mrow = wm + (lane & 15);
    const int nrow = wn + (lane & 15);
    const int kg   = (lane >> 4) * 8;

    const short* aPtr = A  + (size_t)(rowBase + srow) * K + skq;
    const short* bPtr = Bt + (size_t)(colBase + srow) * K + skq;

    for (int k0 = 0; k0 < K; k0 += 32) {
        short8 a0 = *(const short8*)(aPtr + k0);
        short8 a1 = *(const short8*)(aPtr + (size_t)64 * K + k0);
        short8 b0 = *(const short8*)(bPtr + k0);
        short8 b1 = *(const short8*)(bPtr + (size_t)64 * K + k0);

        __syncthreads();
        *(short8*)&As[t * 8]        = a0;
        *(short8*)&As[2048 + t * 8] = a1;
        *(short8*)&Bs[t * 8]        = b0;
        *(short8*)&Bs[2048 + t * 8] = b1;
        __syncthreads();

        short8 a[4], b[4];
        #pragma unroll
        for (int i = 0; i < 4; i++)
            a[i] = *(const short8*)&As[(mrow + i * 16) * 32 + kg];
        #pragma unroll
        for (int j = 0; j < 4; j++)
            b[j] = *(const short8*)&Bs[(nrow + j * 16) * 32 + kg];

        #pragma unroll
        for (int i = 0; i < 4; i++)
            #pragma unroll
            for (int j = 0; j < 4; j++)
                acc[i][j] = __builtin_amdgcn_mfma_f32_16x16x32_bf16(
                    a[i], b[j], acc[i][j], 0, 0, 0);
    }

    // epilogue: C/D layout col=lane&15, row=(lane>>4)*4+reg
    #pragma unroll
    for (int i = 0; i < 4; i++) {
        const int r0 = rowBase + wm + i * 16 + (lane >> 4) * 4;
        #pragma unroll
        for (int j = 0; j < 4; j++) {
            const int c = colBase + wn + j * 16 + (lane & 15);
            const float bv = bias[c];
            #pragma unroll
            for (int reg = 0; reg < 4; reg++) {
                float val = acc[i][j][reg] + bv;
                const int row = r0 + reg;
                if (mode == 0) {
                    outF[(size_t)row * N + c] = val;
                } else {
                    if (mode == 1) val = (val > 0.f) ? val + 1.f : expf(val);
                    const int b_ = row >> 9;       // SEQ=512
                    const int n_ = row & 511;
                    const int h_ = c >> 6;         // DK=64
                    const int d_ = c & 63;
                    outB[((size_t)((b_ * NHEADS + h_) * SEQ + n_)) * DK + d_] = f2bf(val);
                }
            }
        }
    }
}

// ---------------------------------------------------------------------------
// Linear attention per (b,h). Inputs qf/kf/v: bf16 [B,H,N,DK].
// Output attn: bf16 [B,N,D_MODEL].
// ---------------------------------------------------------------------------
__global__ __launch_bounds__(256)
void attn_kernel(const short* __restrict__ qf, const short* __restrict__ kf,
                 const short* __restrict__ v, short* __restrict__ attn)
{
    __shared__ float kfS[32][64];
    __shared__ float vS[32][64];
    __shared__ float kvS[64][68];
    __shared__ float ksumS[64];
    __shared__ float qS[64][68];

    const int bh = blockIdx.x;          // 0..511
    const int b  = bh >> 4;
    const int h  = bh & 15;
    const size_t base = (size_t)bh * SEQ * DK;
    const short* qfp = qf + base;
    const short* kfp = kf + base;
    const short* vp  = v  + base;

    const int t  = threadIdx.x;
    const int tr = t >> 4;
    const int tc = t & 15;

    float acc[4][4];
    #pragma unroll
    for (int i = 0; i < 4; i++)
        #pragma unroll
        for (int j = 0; j < 4; j++) acc[i][j] = 0.f;
    float ks[4] = {0.f, 0.f, 0.f, 0.f};

    const int lr = t >> 3;              // 0..31
    const int lc = (t & 7) * 8;         // 0..56

    for (int n0 = 0; n0 < SEQ; n0 += 32) {
        short8 k8 = *(const short8*)&kfp[(size_t)(n0 + lr) * DK + lc];
        short8 v8 = *(const short8*)&vp[(size_t)(n0 + lr) * DK + lc];
        #pragma unroll
        for (int j = 0; j < 8; j++) {
            kfS[lr][lc + j] = bf2f(k8[j]);
            vS[lr][lc + j]  = bf2f(v8[j]);
        }
        __syncthreads();
        #pragma unroll 8
        for (int nn = 0; nn < 32; nn++) {
            float a0 = kfS[nn][tr * 4 + 0];
            float a1 = kfS[nn][tr * 4 + 1];
            float a2 = kfS[nn][tr * 4 + 2];
            float a3 = kfS[nn][tr * 4 + 3];
            float4 b4 = *(float4*)&vS[nn][tc * 4];
            acc[0][0] += a0 * b4.x; acc[0][1] += a0 * b4.y; acc[0][2] += a0 * b4.z; acc[0][3] += a0 * b4.w;
            acc[1][0] += a1 * b4.x; acc[1][1] += a1 * b4.y; acc[1][2] += a1 * b4.z; acc[1][3] += a1 * b4.w;
            acc[2][0] += a2 * b4.x; acc[2][1] += a2 * b4.y; acc[2][2] += a2 * b4.z; acc[2][3] += a2 * b4.w;
            acc[3][0] += a3 * b4.x; acc[3][1] += a3 * b4.y; acc[3][2] += a3 * b4.z; acc[3][3] += a3 * b4.w;
            if (tc == 0) { ks[0] += a0; ks[1] += a1; ks[2] += a2; ks[3] += a3; }
        }
        __syncthreads();
    }

    #pragma unroll
    for (int i = 0; i < 4; i++)
        #pragma unroll
        for (int j = 0; j < 4; j++)
            kvS[tr * 4 + i][tc * 4 + j] = acc[i][j];
    if (tc == 0) {
        #pragma unroll
        for (int i = 0; i < 4; i++) ksumS[tr * 4 + i] = ks[i];
    }

    const int qlr = t >> 2;             // 0..63
    const int qlc = (t & 3) * 16;       // 0,16,32,48

    for (int n0 = 0; n0 < SEQ; n0 += 64) {
        __syncthreads();
        short8 q0 = *(const short8*)&qfp[(size_t)(n0 + qlr) * DK + qlc];
        short8 q1 = *(const short8*)&qfp[(size_t)(n0 + qlr) * DK + qlc + 8];
        #pragma unroll
        for (int j = 0; j < 8; j++) {
            qS[qlr][qlc + j]     = bf2f(q0[j]);
            qS[qlr][qlc + 8 + j] = bf2f(q1[j]);
        }
        __syncthreads();

        float4 o[4];
        float den[4];
        #pragma unroll
        for (int i = 0; i < 4; i++) {
            o[i] = make_float4(0.f, 0.f, 0.f, 0.f);
            den[i] = LIN_EPS;
        }
        #pragma unroll 4
        for (int d = 0; d < 64; d++) {
            float4 b4 = *(float4*)&kvS[d][tc * 4];
            float ksd = ksumS[d];
            #pragma unroll
            for (int i = 0; i < 4; i++) {
                float a = qS[tr * 4 + i][d];
                o[i].x += a * b4.x;
                o[i].y += a * b4.y;
                o[i].z += a * b4.z;
                o[i].w += a * b4.w;
                den[i] += a * ksd;
            }
        }
        #pragma unroll
        for (int i = 0; i < 4; i++) {
            const float inv = 1.f / den[i];
            const int n = n0 + tr * 4 + i;
            short* dst = attn + ((size_t)(b * SEQ + n)) * D_MODEL + h * DK;
            short4v s;
            s.x = f2bf(o[i].x * inv);
            s.y = f2bf(o[i].y * inv);
            s.z = f2bf(o[i].z * inv);
            s.w = f2bf(o[i].w * inv);
            *(short4v*)&dst[tc * 4] = s;
        }
    }
}

extern "C" void kernel_launch(void* const* d_in, const int* in_sizes, int n_in,
                              void* d_out, int out_size, void* d_ws, size_t ws_size,
                              hipStream_t stream)
{
    const float* x   = (const float*)d_in[0];
    const float* W_q = (const float*)d_in[1];
    const float* b_q = (const float*)d_in[2];
    const float* W_k = (const float*)d_in[3];
    const float* b_k = (const float*)d_in[4];
    const float* W_v = (const float*)d_in[5];
    const float* b_v = (const float*)d_in[6];
    const float* W_o = (const float*)d_in[7];
    const float* b_o = (const float*)d_in[8];
    float* out = (float*)d_out;

    const size_t MN = (size_t)M_TOTAL * D_MODEL;   // 16,777,216
    const size_t WN = (size_t)D_MODEL * D_MODEL;   // 1,048,576

    // Workspace budget: R1's 256 MB passed; R3/R4's 264 MB crashed.
    // Total here: 32 + 8 + 96 + 32 = 168 MB.
    char* ws = (char*)d_ws;
    short* xb    = (short*)ws;                 ws += MN * 2;        // 32 MB
    short* Wtq   = (short*)ws;                 ws += WN * 2;        // 2 MB
    short* Wtk   = (short*)ws;                 ws += WN * 2;
    short* Wtv   = (short*)ws;                 ws += WN * 2;
    short* Wto   = (short*)ws;                 ws += WN * 2;
    short* qfb   = (short*)ws;                 ws += MN * 2;        // 32 MB
    short* kfb   = (short*)ws;                 ws += MN * 2;
    short* vvb   = (short*)ws;                 ws += MN * 2;
    short* attnb = (short*)ws;                 ws += MN * 2;        // 32 MB

    cast_bf16<<<dim3((int)(MN / 4 / 256)), dim3(256), 0, stream>>>(x, xb, (int)(MN / 4));
    dim3 tblk(32, 8), tgrd(32, 32);
    transpose_w<<<tgrd, tblk, 0, stream>>>(W_q, Wtq);
    transpose_w<<<tgrd, tblk, 0, stream>>>(W_k, Wtk);
    transpose_w<<<tgrd, tblk, 0, stream>>>(W_v, Wtv);
    transpose_w<<<tgrd, tblk, 0, stream>>>(W_o, Wto);

    dim3 gblk(256), ggrd(D_MODEL / 128, M_TOTAL / 128);   // (8, 128)
    gemm_nt_bf16<<<ggrd, gblk, 0, stream>>>(xb, Wtq, b_q, nullptr, qfb, 1);
    gemm_nt_bf16<<<ggrd, gblk, 0, stream>>>(xb, Wtk, b_k, nullptr, kfb, 1);
    gemm_nt_bf16<<<ggrd, gblk, 0, stream>>>(xb, Wtv, b_v, nullptr, vvb, 2);

    attn_kernel<<<dim3(BATCH * NHEADS), dim3(256), 0, stream>>>(qfb, kfb, vvb, attnb);

    gemm_nt_bf16<<<ggrd, gblk, 0, stream>>>(attnb, Wto, b_o, out, nullptr, 0);
}

// Round 6
// 413.668 us; speedup vs baseline: 12.0961x; 1.2171x over previous
//
#include <hip/hip_runtime.h>
#include <hip/hip_bf16.h>
#include <cmath>

#define D_MODEL 1024
#define NHEADS  16
#define DK      64
#define BATCH   32
#define SEQ     512
#define M_TOTAL (BATCH * SEQ)   // 16384
#define LIN_EPS 1e-6f

typedef __attribute__((ext_vector_type(8))) short short8;
typedef __attribute__((ext_vector_type(4))) short short4v;
typedef __attribute__((ext_vector_type(4))) float floatx4;

__device__ inline short f2bf(float f) {
    __hip_bfloat16 h = __float2bfloat16(f);
    return *reinterpret_cast<short*>(&h);
}
__device__ inline float bf2f(short s) {
    unsigned int u = ((unsigned int)(unsigned short)s) << 16;
    union { unsigned int u; float f; } c; c.u = u;
    return c.f;
}

#define GLOBAL_LOAD_LDS16(gptr, lptr)                                          \
    __builtin_amdgcn_global_load_lds(                                          \
        (const __attribute__((address_space(1))) unsigned int*)(gptr),         \
        (__attribute__((address_space(3))) unsigned int*)(lptr), 16, 0, 0)

// ---------------------------------------------------------------------------
// fp32 -> bf16 cast
// ---------------------------------------------------------------------------
__global__ __launch_bounds__(256)
void cast_bf16(const float* __restrict__ in, short* __restrict__ out, int n4)
{
    int i = blockIdx.x * 256 + threadIdx.x;
    if (i >= n4) return;
    float4 f = *(const float4*)&in[(size_t)i * 4];
    short4v s;
    s.x = f2bf(f.x); s.y = f2bf(f.y); s.z = f2bf(f.z); s.w = f2bf(f.w);
    *(short4v*)&out[(size_t)i * 4] = s;
}

// ---------------------------------------------------------------------------
// All four W[K][N] fp32 -> Wt[N][K] bf16; z selects matrix. Wt's contiguous.
// ---------------------------------------------------------------------------
__global__ __launch_bounds__(256)
void transpose_w4(const float* __restrict__ W0, const float* __restrict__ W1,
                  const float* __restrict__ W2, const float* __restrict__ W3,
                  short* __restrict__ WtBase)
{
    __shared__ float tile[32][33];
    const int z = blockIdx.z;
    const float* W = (z == 0) ? W0 : (z == 1) ? W1 : (z == 2) ? W2 : W3;
    short* Wt = WtBase + (size_t)z * D_MODEL * D_MODEL;
    const int tx = threadIdx.x, ty = threadIdx.y;   // 32 x 8
    const int nb = blockIdx.x * 32, kb = blockIdx.y * 32;
    #pragma unroll
    for (int r = 0; r < 32; r += 8)
        tile[ty + r][tx] = W[(size_t)(kb + ty + r) * D_MODEL + nb + tx];
    __syncthreads();
    #pragma unroll
    for (int r = 0; r < 32; r += 8)
        Wt[(size_t)(nb + ty + r) * D_MODEL + kb + tx] = f2bf(tile[tx][ty + r]);
}

// ---------------------------------------------------------------------------
// Fused QKV GEMM: A[16384,1024] bf16 @ Wt[3072,1024]^T, m97-style K-loop
// (global_load_lds width=16, 2-barrier). 128x128 tile, BK=32, 4 waves,
// wave = 64x64 quadrant = 4x4 mfma_f32_16x16x32_bf16.
// Epilogue: + bias; segments q,k (seg<2) get phi=elu+1; bf16 store permuted
// to [seg][B,H,N,DK] (qfb|kfb|vvb contiguous).
// ---------------------------------------------------------------------------
__global__ __launch_bounds__(256)
void qkv_gemm(const short* __restrict__ A, const short* __restrict__ Wt,
              const float* __restrict__ b_q, const float* __restrict__ b_k,
              const float* __restrict__ b_v, short* __restrict__ outB)
{
    constexpr int K = 1024;
    constexpr size_t MN = (size_t)M_TOTAL * D_MODEL;
    __shared__ short As[128 * 32];
    __shared__ short Bs[128 * 32];

    const int t    = threadIdx.x;
    const int wave = t >> 6;
    const int lane = t & 63;
    const int rowBase = blockIdx.y * 128;
    const int colBase = blockIdx.x * 128;    // 0..3071
    const int wm = (wave >> 1) * 64;
    const int wn = (wave & 1) * 64;

    floatx4 acc[4][4];
    #pragma unroll
    for (int i = 0; i < 4; i++)
        #pragma unroll
        for (int j = 0; j < 4; j++) acc[i][j] = (floatx4){0.f, 0.f, 0.f, 0.f};

    const int srow = t >> 2;          // 0..63
    const int skq  = (t & 3) * 8;     // 0,8,16,24
    const int mrow = wm + (lane & 15);
    const int nrow = wn + (lane & 15);
    const int kg   = (lane >> 4) * 8;

    const short* aPtr = A  + (size_t)(rowBase + srow) * K + skq;
    const short* bPtr = Wt + (size_t)(colBase + srow) * K + skq;

    for (int k0 = 0; k0 < K; k0 += 32) {
        __syncthreads();   // prior iteration's ds_reads complete
        GLOBAL_LOAD_LDS16(aPtr + k0,                    &As[t * 8]);
        GLOBAL_LOAD_LDS16(aPtr + (size_t)64 * K + k0,   &As[2048 + t * 8]);
        GLOBAL_LOAD_LDS16(bPtr + k0,                    &Bs[t * 8]);
        GLOBAL_LOAD_LDS16(bPtr + (size_t)64 * K + k0,   &Bs[2048 + t * 8]);
        __syncthreads();   // vmcnt(0) drain: DMA landed

        short8 a[4], b[4];
        #pragma unroll
        for (int i = 0; i < 4; i++)
            a[i] = *(const short8*)&As[(mrow + i * 16) * 32 + kg];
        #pragma unroll
        for (int j = 0; j < 4; j++)
            b[j] = *(const short8*)&Bs[(nrow + j * 16) * 32 + kg];

        #pragma unroll
        for (int i = 0; i < 4; i++)
            #pragma unroll
            for (int j = 0; j < 4; j++)
                acc[i][j] = __builtin_amdgcn_mfma_f32_16x16x32_bf16(
                    a[i], b[j], acc[i][j], 0, 0, 0);
    }

    const int seg = colBase >> 10;            // 0=q 1=k 2=v (tiles never straddle)
    const float* bias = (seg == 0) ? b_q : (seg == 1) ? b_k : b_v;
    short* outSeg = outB + (size_t)seg * MN;

    // C/D layout: col=lane&15, row=(lane>>4)*4+reg
    #pragma unroll
    for (int i = 0; i < 4; i++) {
        const int r0 = rowBase + wm + i * 16 + (lane >> 4) * 4;
        #pragma unroll
        for (int j = 0; j < 4; j++) {
            const int cl = (colBase & 1023) + wn + j * 16 + (lane & 15);
            const float bv = bias[cl];
            const int h_ = cl >> 6;
            const int d_ = cl & 63;
            #pragma unroll
            for (int reg = 0; reg < 4; reg++) {
                float val = acc[i][j][reg] + bv;
                if (seg < 2) val = (val > 0.f) ? val + 1.f : expf(val);
                const int row = r0 + reg;
                const int b_ = row >> 9;       // SEQ=512
                const int n_ = row & 511;
                outSeg[((size_t)((b_ * NHEADS + h_) * SEQ + n_)) * DK + d_] = f2bf(val);
            }
        }
    }
}

// ---------------------------------------------------------------------------
// Output GEMM: out[16384,1024] fp32 = attn bf16 @ Wto^T + b_o. Same K-loop.
// ---------------------------------------------------------------------------
__global__ __launch_bounds__(256)
void o_gemm(const short* __restrict__ A, const short* __restrict__ Wt,
            const float* __restrict__ bias, float* __restrict__ out)
{
    constexpr int K = 1024;
    constexpr int N = 1024;
    __shared__ short As[128 * 32];
    __shared__ short Bs[128 * 32];

    const int t    = threadIdx.x;
    const int wave = t >> 6;
    const int lane = t & 63;
    const int rowBase = blockIdx.y * 128;
    const int colBase = blockIdx.x * 128;
    const int wm = (wave >> 1) * 64;
    const int wn = (wave & 1) * 64;

    floatx4 acc[4][4];
    #pragma unroll
    for (int i = 0; i < 4; i++)
        #pragma unroll
        for (int j = 0; j < 4; j++) acc[i][j] = (floatx4){0.f, 0.f, 0.f, 0.f};

    const int srow = t >> 2;
    const int skq  = (t & 3) * 8;
    const int mrow = wm + (lane & 15);
    const int nrow = wn + (lane & 15);
    const int kg   = (lane >> 4) * 8;

    const short* aPtr = A  + (size_t)(rowBase + srow) * K + skq;
    const short* bPtr = Wt + (size_t)(colBase + srow) * K + skq;

    for (int k0 = 0; k0 < K; k0 += 32) {
        __syncthreads();
        GLOBAL_LOAD_LDS16(aPtr + k0,                    &As[t * 8]);
        GLOBAL_LOAD_LDS16(aPtr + (size_t)64 * K + k0,   &As[2048 + t * 8]);
        GLOBAL_LOAD_LDS16(bPtr + k0,                    &Bs[t * 8]);
        GLOBAL_LOAD_LDS16(bPtr + (size_t)64 * K + k0,   &Bs[2048 + t * 8]);
        __syncthreads();

        short8 a[4], b[4];
        #pragma unroll
        for (int i = 0; i < 4; i++)
            a[i] = *(const short8*)&As[(mrow + i * 16) * 32 + kg];
        #pragma unroll
        for (int j = 0; j < 4; j++)
            b[j] = *(const short8*)&Bs[(nrow + j * 16) * 32 + kg];

        #pragma unroll
        for (int i = 0; i < 4; i++)
            #pragma unroll
            for (int j = 0; j < 4; j++)
                acc[i][j] = __builtin_amdgcn_mfma_f32_16x16x32_bf16(
                    a[i], b[j], acc[i][j], 0, 0, 0);
    }

    #pragma unroll
    for (int i = 0; i < 4; i++) {
        const int r0 = rowBase + wm + i * 16 + (lane >> 4) * 4;
        #pragma unroll
        for (int j = 0; j < 4; j++) {
            const int c = colBase + wn + j * 16 + (lane & 15);
            const float bv = bias[c];
            #pragma unroll
            for (int reg = 0; reg < 4; reg++)
                out[(size_t)(r0 + reg) * N + c] = acc[i][j][reg] + bv;
        }
    }
}

// ---------------------------------------------------------------------------
// Linear attention per (b,h). Inputs qf/kf/v: bf16 [B,H,N,DK].
// Output attn: bf16 [B,N,D_MODEL]. (unchanged from R5)
// ---------------------------------------------------------------------------
__global__ __launch_bounds__(256)
void attn_kernel(const short* __restrict__ qf, const short* __restrict__ kf,
                 const short* __restrict__ v, short* __restrict__ attn)
{
    __shared__ float kfS[32][64];
    __shared__ float vS[32][64];
    __shared__ float kvS[64][68];
    __shared__ float ksumS[64];
    __shared__ float qS[64][68];

    const int bh = blockIdx.x;          // 0..511
    const int b  = bh >> 4;
    const int h  = bh & 15;
    const size_t base = (size_t)bh * SEQ * DK;
    const short* qfp = qf + base;
    const short* kfp = kf + base;
    const short* vp  = v  + base;

    const int t  = threadIdx.x;
    const int tr = t >> 4;
    const int tc = t & 15;

    float acc[4][4];
    #pragma unroll
    for (int i = 0; i < 4; i++)
        #pragma unroll
        for (int j = 0; j < 4; j++) acc[i][j] = 0.f;
    float ks[4] = {0.f, 0.f, 0.f, 0.f};

    const int lr = t >> 3;              // 0..31
    const int lc = (t & 7) * 8;         // 0..56

    for (int n0 = 0; n0 < SEQ; n0 += 32) {
        short8 k8 = *(const short8*)&kfp[(size_t)(n0 + lr) * DK + lc];
        short8 v8 = *(const short8*)&vp[(size_t)(n0 + lr) * DK + lc];
        #pragma unroll
        for (int j = 0; j < 8; j++) {
            kfS[lr][lc + j] = bf2f(k8[j]);
            vS[lr][lc + j]  = bf2f(v8[j]);
        }
        __syncthreads();
        #pragma unroll 8
        for (int nn = 0; nn < 32; nn++) {
            float a0 = kfS[nn][tr * 4 + 0];
            float a1 = kfS[nn][tr * 4 + 1];
            float a2 = kfS[nn][tr * 4 + 2];
            float a3 = kfS[nn][tr * 4 + 3];
            float4 b4 = *(float4*)&vS[nn][tc * 4];
            acc[0][0] += a0 * b4.x; acc[0][1] += a0 * b4.y; acc[0][2] += a0 * b4.z; acc[0][3] += a0 * b4.w;
            acc[1][0] += a1 * b4.x; acc[1][1] += a1 * b4.y; acc[1][2] += a1 * b4.z; acc[1][3] += a1 * b4.w;
            acc[2][0] += a2 * b4.x; acc[2][1] += a2 * b4.y; acc[2][2] += a2 * b4.z; acc[2][3] += a2 * b4.w;
            acc[3][0] += a3 * b4.x; acc[3][1] += a3 * b4.y; acc[3][2] += a3 * b4.z; acc[3][3] += a3 * b4.w;
            if (tc == 0) { ks[0] += a0; ks[1] += a1; ks[2] += a2; ks[3] += a3; }
        }
        __syncthreads();
    }

    #pragma unroll
    for (int i = 0; i < 4; i++)
        #pragma unroll
        for (int j = 0; j < 4; j++)
            kvS[tr * 4 + i][tc * 4 + j] = acc[i][j];
    if (tc == 0) {
        #pragma unroll
        for (int i = 0; i < 4; i++) ksumS[tr * 4 + i] = ks[i];
    }

    const int qlr = t >> 2;             // 0..63
    const int qlc = (t & 3) * 16;       // 0,16,32,48

    for (int n0 = 0; n0 < SEQ; n0 += 64) {
        __syncthreads();
        short8 q0 = *(const short8*)&qfp[(size_t)(n0 + qlr) * DK + qlc];
        short8 q1 = *(const short8*)&qfp[(size_t)(n0 + qlr) * DK + qlc + 8];
        #pragma unroll
        for (int j = 0; j < 8; j++) {
            qS[qlr][qlc + j]     = bf2f(q0[j]);
            qS[qlr][qlc + 8 + j] = bf2f(q1[j]);
        }
        __syncthreads();

        float4 o[4];
        float den[4];
        #pragma unroll
        for (int i = 0; i < 4; i++) {
            o[i] = make_float4(0.f, 0.f, 0.f, 0.f);
            den[i] = LIN_EPS;
        }
        #pragma unroll 4
        for (int d = 0; d < 64; d++) {
            float4 b4 = *(float4*)&kvS[d][tc * 4];
            float ksd = ksumS[d];
            #pragma unroll
            for (int i = 0; i < 4; i++) {
                float a = qS[tr * 4 + i][d];
                o[i].x += a * b4.x;
                o[i].y += a * b4.y;
                o[i].z += a * b4.z;
                o[i].w += a * b4.w;
                den[i] += a * ksd;
            }
        }
        #pragma unroll
        for (int i = 0; i < 4; i++) {
            const float inv = 1.f / den[i];
            const int n = n0 + tr * 4 + i;
            short* dst = attn + ((size_t)(b * SEQ + n)) * D_MODEL + h * DK;
            short4v s;
            s.x = f2bf(o[i].x * inv);
            s.y = f2bf(o[i].y * inv);
            s.z = f2bf(o[i].z * inv);
            s.w = f2bf(o[i].w * inv);
            *(short4v*)&dst[tc * 4] = s;
        }
    }
}

extern "C" void kernel_launch(void* const* d_in, const int* in_sizes, int n_in,
                              void* d_out, int out_size, void* d_ws, size_t ws_size,
                              hipStream_t stream)
{
    const float* x   = (const float*)d_in[0];
    const float* W_q = (const float*)d_in[1];
    const float* b_q = (const float*)d_in[2];
    const float* W_k = (const float*)d_in[3];
    const float* b_k = (const float*)d_in[4];
    const float* W_v = (const float*)d_in[5];
    const float* b_v = (const float*)d_in[6];
    const float* W_o = (const float*)d_in[7];
    const float* b_o = (const float*)d_in[8];
    float* out = (float*)d_out;

    const size_t MN = (size_t)M_TOTAL * D_MODEL;   // 16,777,216
    const size_t WN = (size_t)D_MODEL * D_MODEL;   // 1,048,576

    // Workspace: 32 + 8 + 96 + 32 = 168 MB (R5-proven budget; 264 MB crashed).
    char* ws = (char*)d_ws;
    short* xb    = (short*)ws;                 ws += MN * 2;        // 32 MB
    short* Wt    = (short*)ws;                 ws += WN * 2 * 4;    // 8 MB: q|k|v|o
    short* qkvB  = (short*)ws;                 ws += MN * 2 * 3;    // 96 MB: qf|kf|vv
    short* attnb = (short*)ws;                 ws += MN * 2;        // 32 MB

    short* Wto = Wt + WN * 3;
    short* qfb = qkvB;
    short* kfb = qkvB + MN;
    short* vvb = qkvB + MN * 2;

    cast_bf16<<<dim3((int)(MN / 4 / 256)), dim3(256), 0, stream>>>(x, xb, (int)(MN / 4));
    transpose_w4<<<dim3(32, 32, 4), dim3(32, 8), 0, stream>>>(W_q, W_k, W_v, W_o, Wt);

    qkv_gemm<<<dim3(24, 128), dim3(256), 0, stream>>>(xb, Wt, b_q, b_k, b_v, qkvB);

    attn_kernel<<<dim3(BATCH * NHEADS), dim3(256), 0, stream>>>(qfb, kfb, vvb, attnb);

    o_gemm<<<dim3(8, 128), dim3(256), 0, stream>>>(attnb, Wto, b_o, out);
}